// Round 6
// baseline (764.527 us; speedup 1.0000x reference)
//
#include <hip/hip_runtime.h>
#include <math.h>

#define N_NODES 1024
#define BATCH   64
#define F_IN    128     // D_IN + UNITS (K of the projection GEMM)
#define UNITS   64
#define NUM_M   5
#define CAP     192     // ELL row capacity (max row degree ~55 for this seed)
#define NT1     640     // 5*128 output cols, gconv1
#define NT2     320     // 5*64  output cols, gconv2

typedef __attribute__((ext_vector_type(8))) short short8v;
typedef __attribute__((ext_vector_type(4))) float f32x4;

__device__ __forceinline__ unsigned short bf16_rne(float x) {
    unsigned u = __float_as_uint(x);
    return (unsigned short)((u + 0x7FFFu + ((u >> 16) & 1u)) >> 16);
}

// ---------------- ELL build: column-major packed (col,val) pairs ------------
__global__ void ell_build(const float* __restrict__ L, int* __restrict__ cnt,
                          float2* __restrict__ ell) {
    int row  = blockIdx.x * (blockDim.x >> 6) + (threadIdx.x >> 6);
    int lane = threadIdx.x & 63;
    if (row >= N_NODES) return;
    const float* Lr = L + (size_t)row * N_NODES;
    int base = 0;
    for (int seg = 0; seg < N_NODES; seg += 64) {
        float v = Lr[seg + lane];
        bool nz = (v != 0.0f);
        unsigned long long bal = __ballot(nz);
        int off = __popcll(bal & ((1ull << lane) - 1ull));
        if (nz) {
            int idx = base + off;
            if (idx < CAP) ell[(size_t)idx * N_NODES + row] =
                               make_float2(__int_as_float(seg + lane), v);
        }
        base += __popcll(bal);
    }
    if (base > CAP) base = CAP;
    int padded = (base + 3) & ~3;
    if (padded > CAP) padded = CAP;
    for (int idx = base + lane; idx < padded; idx += 64)
        ell[(size_t)idx * N_NODES + row] = make_float2(__int_as_float(0), 0.0f);
    if (lane == 0) cnt[row] = padded;
}

// ---------------- W' prep: fold + bf16 hi/lo split + MFMA fragment order ----
// W [640][nout], row = k*5 + m. Folded W'[k][jg], jg = m*nout + j:
//   m0 = W0-W3-W4, m1 = W1, m2 = W2, m3 = 2*W3, m4 = 2*W4
// Fragment layout (16x16x32 bf16 B-operand): element (k, jg) at
//   ((((jg>>4)*4 + (k>>5))*64) + ((k>>3)&3)*16 + (jg&15))*8 + (k&7)
__global__ void wprep_frag(const float* __restrict__ W, unsigned short* __restrict__ Wh,
                           unsigned short* __restrict__ Wl, int nout, int ntot) {
    int idx = blockIdx.x * blockDim.x + threadIdx.x;
    if (idx >= F_IN * ntot) return;
    int jg = idx % ntot, k = idx / ntot;
    int m = jg / nout, j = jg % nout;
    const float* Wk = W + (size_t)(k * NUM_M) * nout;
    float v;
    if (m == 0)      v = Wk[0 * nout + j] - Wk[3 * nout + j] - Wk[4 * nout + j];
    else if (m == 3) v = 2.0f * Wk[3 * nout + j];
    else if (m == 4) v = 2.0f * Wk[4 * nout + j];
    else             v = Wk[(size_t)m * nout + j];
    unsigned short h = bf16_rne(v);
    float hf = __uint_as_float((unsigned)h << 16);
    unsigned short lo = bf16_rne(v - hf);
    size_t fi = ((((size_t)(jg >> 4) * 4 + (k >> 5)) * 64) + ((k >> 3) & 3) * 16 + (jg & 15)) * 8 + (k & 7);
    Wh[fi] = h; Wl[fi] = lo;
}

// ---------------- MFMA projection: P = xin @ W' (bf16x3, K=128) ------------
// grid = (NT/64, nrows/128); block 256 (4 waves, 2x2); tile 128 rows x 64 cols.
// P written in tiled layout: P[(jg>>3)*nrows*8 + i*8 + (jg&7)]
template <int RMUL>
__global__ __launch_bounds__(256, 2) void gemm_proj(
        const float* __restrict__ inp, const float* __restrict__ hx,
        const float* __restrict__ r1t,       // OUT1 tiled; tiles 0-7 = r
        const unsigned short* __restrict__ Wh, const unsigned short* __restrict__ Wl,
        float* __restrict__ P, int nrows, int row0) {
    __shared__ __align__(16) unsigned short Ahi[128 * 128];   // 32 KB
    __shared__ __align__(16) unsigned short Alo[128 * 128];   // 32 KB
    const int tid = threadIdx.x;
    const int i0 = blockIdx.y * 128;
    const int by = blockIdx.x;

    // stage A (xin rows) as bf16 hi/lo, XOR-swizzled 16B slots
    for (int v = tid; v < 2048; v += 256) {
        int row = v >> 4, kg = v & 15;
        int il = i0 + row;
        size_t g = (size_t)(row0 + il);
        float x[8];
        if (kg < 8) {
            *(float4*)&x[0] = *(const float4*)(inp + g * 64 + kg * 8);
            *(float4*)&x[4] = *(const float4*)(inp + g * 64 + kg * 8 + 4);
        } else {
            *(float4*)&x[0] = *(const float4*)(hx + g * 64 + (kg - 8) * 8);
            *(float4*)&x[4] = *(const float4*)(hx + g * 64 + (kg - 8) * 8 + 4);
            if (RMUL) {
                const float* rp = r1t + ((size_t)(kg - 8) * nrows + il) * 8;
                float4 r0 = *(const float4*)(rp), r4 = *(const float4*)(rp + 4);
                x[0] *= r0.x; x[1] *= r0.y; x[2] *= r0.z; x[3] *= r0.w;
                x[4] *= r4.x; x[5] *= r4.y; x[6] *= r4.z; x[7] *= r4.w;
            }
        }
        short8v hv, lv;
        #pragma unroll
        for (int e = 0; e < 8; ++e) {
            unsigned short h = bf16_rne(x[e]);
            float hf = __uint_as_float((unsigned)h << 16);
            hv[e] = (short)h;
            lv[e] = (short)bf16_rne(x[e] - hf);
        }
        int slot = kg ^ (row & 7);
        *(short8v*)(Ahi + row * 128 + slot * 8) = hv;
        *(short8v*)(Alo + row * 128 + slot * 8) = lv;
    }
    __syncthreads();

    const int lane = tid & 63, wid = tid >> 6;
    const int wm = wid >> 1, wn = wid & 1;

    // B fragments from pre-packed Wh/Wl (L2-resident)
    short8v bh[4][2], bl[4][2];
    #pragma unroll
    for (int s = 0; s < 4; ++s)
        #pragma unroll
        for (int jc = 0; jc < 2; ++jc) {
            int cg16 = by * 4 + wn * 2 + jc;
            size_t o = (((size_t)cg16 * 4 + s) * 64 + lane) * 8;
            bh[s][jc] = *(const short8v*)(Wh + o);
            bl[s][jc] = *(const short8v*)(Wl + o);
        }

    f32x4 acc[4][2];
    #pragma unroll
    for (int i = 0; i < 4; ++i)
        #pragma unroll
        for (int jc = 0; jc < 2; ++jc)
            acc[i][jc] = (f32x4){0.f, 0.f, 0.f, 0.f};

    #pragma unroll
    for (int s = 0; s < 4; ++s) {
        short8v ah[4], al[4];
        #pragma unroll
        for (int i = 0; i < 4; ++i) {
            int row = wm * 64 + i * 16 + (lane & 15);
            int kg = s * 4 + (lane >> 4);
            int slot = kg ^ (row & 7);
            ah[i] = *(const short8v*)(Ahi + row * 128 + slot * 8);
            al[i] = *(const short8v*)(Alo + row * 128 + slot * 8);
        }
        #pragma unroll
        for (int i = 0; i < 4; ++i)
            #pragma unroll
            for (int jc = 0; jc < 2; ++jc) {
                acc[i][jc] = __builtin_amdgcn_mfma_f32_16x16x32_bf16(al[i], bh[s][jc], acc[i][jc], 0, 0, 0);
                acc[i][jc] = __builtin_amdgcn_mfma_f32_16x16x32_bf16(ah[i], bl[s][jc], acc[i][jc], 0, 0, 0);
                acc[i][jc] = __builtin_amdgcn_mfma_f32_16x16x32_bf16(ah[i], bh[s][jc], acc[i][jc], 0, 0, 0);
            }
    }

    // write P tiled: D frag (row = (lane>>4)*4+q, col = lane&15)
    #pragma unroll
    for (int i = 0; i < 4; ++i)
        #pragma unroll
        for (int jc = 0; jc < 2; ++jc) {
            int jg = by * 64 + wn * 32 + jc * 16 + (lane & 15);
            size_t tb = (size_t)(jg >> 3) * nrows * 8 + (jg & 7);
            int rbase = i0 + wm * 64 + i * 16 + (lane >> 4) * 4;
            #pragma unroll
            for (int q = 0; q < 4; ++q)
                P[tb + (size_t)(rbase + q) * 8] = acc[i][jc][q];
        }
}

// ---------------- shared gather core (FT=8, 2 lanes per row) ---------------
__device__ __forceinline__ void gather8(
        const int* __restrict__ cnt, const float2* __restrict__ ell,
        const float* __restrict__ ldsX, int mg, int fg, float4* accR) {
    #pragma unroll
    for (int k = 0; k < 8; ++k) {
        int m = mg + k * 128;
        int nn = cnt[m];
        float4 acc = make_float4(0.f, 0.f, 0.f, 0.f);
        for (int j = 0; j < nn; j += 4) {        // nn is a multiple of 4
            float2 p0 = ell[(size_t)(j + 0) * N_NODES + m];
            float2 p1 = ell[(size_t)(j + 1) * N_NODES + m];
            float2 p2 = ell[(size_t)(j + 2) * N_NODES + m];
            float2 p3 = ell[(size_t)(j + 3) * N_NODES + m];
            float4 x0 = *(const float4*)(ldsX + __float_as_int(p0.x) * 8 + fg * 4);
            float4 x1 = *(const float4*)(ldsX + __float_as_int(p1.x) * 8 + fg * 4);
            float4 x2 = *(const float4*)(ldsX + __float_as_int(p2.x) * 8 + fg * 4);
            float4 x3 = *(const float4*)(ldsX + __float_as_int(p3.x) * 8 + fg * 4);
            acc.x += p0.y * x0.x; acc.y += p0.y * x0.y; acc.z += p0.y * x0.z; acc.w += p0.y * x0.w;
            acc.x += p1.y * x1.x; acc.y += p1.y * x1.y; acc.z += p1.y * x1.z; acc.w += p1.y * x1.w;
            acc.x += p2.y * x2.x; acc.y += p2.y * x2.y; acc.z += p2.y * x2.z; acc.w += p2.y * x2.w;
            acc.x += p3.y * x3.x; acc.y += p3.y * x3.y; acc.z += p3.y * x3.z; acc.w += p3.y * x3.w;
        }
        accR[k] = acc;
    }
}

// ---------------- diffuse_t: dst_tile = L @ src_tile (+ add_tile) ----------
// Tiled layout [tile][nrows][8]; grid = (tiles_per_slice, Bc).
// In-place safe: each block stages its own (ft,b) tile before writing it.
template <int ADD>
__global__ __launch_bounds__(256, 4) void diffuse_t(
        const int* __restrict__ cnt, const float2* __restrict__ ell,
        const float* __restrict__ src, float* __restrict__ dst,
        const float* __restrict__ add, int nrows) {
    __shared__ float ldsX[N_NODES * 8];   // 32 KB
    const int tid = threadIdx.x;
    const size_t base = ((size_t)blockIdx.x * nrows + blockIdx.y * N_NODES) * 8;

    for (int v = tid; v < 2048; v += 256)
        *(float4*)(ldsX + v * 4) = *(const float4*)(src + base + v * 4);
    __syncthreads();

    const int fg = tid & 1, mg = tid >> 1;
    float4 accR[8];
    gather8(cnt, ell, ldsX, mg, fg, accR);
    #pragma unroll
    for (int k = 0; k < 8; ++k) {
        size_t o = base + (size_t)(mg + k * 128) * 8 + fg * 4;
        float4 a = accR[k];
        if (ADD) {
            float4 t = *(const float4*)(add + o);
            a.x += t.x; a.y += t.y; a.z += t.z; a.w += t.w;
        }
        *(float4*)(dst + o) = a;
    }
}

// ---------------- combine1: OUT1 = sigmoid(P0+P1+P2+b1), tiled out ---------
__global__ void combine1(const float* __restrict__ P, const float* __restrict__ b1,
                         float* __restrict__ O1, int nrows) {
    int i  = blockIdx.x * 256 + threadIdx.x;
    int ft = blockIdx.y;                       // 0..15
    size_t sl = (size_t)16 * nrows * 8;
    size_t o  = ((size_t)ft * nrows + i) * 8;
    #pragma unroll
    for (int q = 0; q < 8; q += 4) {
        float4 p0 = *(const float4*)(P + o + q);
        float4 p1 = *(const float4*)(P + sl + o + q);
        float4 p2 = *(const float4*)(P + 2 * sl + o + q);
        float4 bb = *(const float4*)(b1 + ft * 8 + q);
        float4 z;
        z.x = 1.f / (1.f + expf(-(p0.x + p1.x + p2.x + bb.x)));
        z.y = 1.f / (1.f + expf(-(p0.y + p1.y + p2.y + bb.y)));
        z.z = 1.f / (1.f + expf(-(p0.z + p1.z + p2.z + bb.z)));
        z.w = 1.f / (1.f + expf(-(p0.w + p1.w + p2.w + bb.w)));
        *(float4*)(O1 + o + q) = z;
    }
}

// ---------------- combine2: out = u*hx + (1-u)*tanh(P0+P1+P2+b2) -----------
__global__ void combine2(const float* __restrict__ P, const float* __restrict__ b2,
                         const float* __restrict__ O1, const float* __restrict__ hx,
                         float* __restrict__ out, int nrows, int row0) {
    int i  = blockIdx.x * 256 + threadIdx.x;
    int ft = blockIdx.y;                       // 0..7
    size_t sl = (size_t)8 * nrows * 8;
    size_t o  = ((size_t)ft * nrows + i) * 8;
    size_t ou = ((size_t)(8 + ft) * nrows + i) * 8;
    size_t g  = (size_t)(row0 + i) * 64 + ft * 8;
    #pragma unroll
    for (int q = 0; q < 8; q += 4) {
        float4 p0 = *(const float4*)(P + o + q);
        float4 p1 = *(const float4*)(P + sl + o + q);
        float4 p2 = *(const float4*)(P + 2 * sl + o + q);
        float4 bb = *(const float4*)(b2 + ft * 8 + q);
        float4 u  = *(const float4*)(O1 + ou + q);
        float4 h  = *(const float4*)(hx + g + q);
        float4 r;
        float c;
        c = tanhf(p0.x + p1.x + p2.x + bb.x); r.x = u.x * h.x + (1.f - u.x) * c;
        c = tanhf(p0.y + p1.y + p2.y + bb.y); r.y = u.y * h.y + (1.f - u.y) * c;
        c = tanhf(p0.z + p1.z + p2.z + bb.z); r.z = u.z * h.z + (1.f - u.z) * c;
        c = tanhf(p0.w + p1.w + p2.w + bb.w); r.w = u.w * h.w + (1.f - u.w) * c;
        *(float4*)(out + g + q) = r;
    }
}

// ---------------------------------------------------------------------------
extern "C" void kernel_launch(void* const* d_in, const int* in_sizes, int n_in,
                              void* d_out, int out_size, void* d_ws, size_t ws_size,
                              hipStream_t stream) {
    const float* inp = (const float*)d_in[0];
    const float* hx  = (const float*)d_in[1];
    const float* L0  = (const float*)d_in[2];
    const float* L1  = (const float*)d_in[3];
    const float* W1  = (const float*)d_in[4];
    const float* b1  = (const float*)d_in[5];
    const float* W2  = (const float*)d_in[6];
    const float* b2  = (const float*)d_in[7];
    float* out = (float*)d_out;

    char* ws = (char*)d_ws;
    size_t off = 0;
    auto carve = [&](size_t bytes) -> char* {
        off = (off + 255) & ~(size_t)255;
        char* p = ws + off;
        off += bytes;
        return p;
    };
    // fixed region
    int*    cnt0 = (int*)   carve(N_NODES * sizeof(int));
    float2* ell0 = (float2*)carve((size_t)N_NODES * CAP * sizeof(float2));
    int*    cnt1 = (int*)   carve(N_NODES * sizeof(int));
    float2* ell1 = (float2*)carve((size_t)N_NODES * CAP * sizeof(float2));
    unsigned short* Wh1 = (unsigned short*)carve((size_t)F_IN * NT1 * 2);
    unsigned short* Wl1 = (unsigned short*)carve((size_t)F_IN * NT1 * 2);
    unsigned short* Wh2 = (unsigned short*)carve((size_t)F_IN * NT2 * 2);
    unsigned short* Wl2 = (unsigned short*)carve((size_t)F_IN * NT2 * 2);

    // chunking (power-of-two Bc)
    size_t per_batch = (size_t)N_NODES * (NT1 + F_IN + NT2) * sizeof(float);   // ~4.45 MB
    size_t fixed_end = (off + 255) & ~(size_t)255;
    size_t avail = (ws_size > fixed_end + 4096) ? (ws_size - fixed_end - 4096) : per_batch;
    int maxb = (int)(avail / per_batch);
    int Bc = 1;
    while (Bc * 2 <= maxb && Bc * 2 <= BATCH) Bc *= 2;

    float* Pg1  = (float*)carve((size_t)Bc * N_NODES * NT1 * sizeof(float));
    float* O1t  = (float*)carve((size_t)Bc * N_NODES * F_IN * sizeof(float));
    float* Pg2  = (float*)carve((size_t)Bc * N_NODES * NT2 * sizeof(float));

    ell_build<<<N_NODES / 4, 256, 0, stream>>>(L0, cnt0, ell0);
    ell_build<<<N_NODES / 4, 256, 0, stream>>>(L1, cnt1, ell1);
    wprep_frag<<<(F_IN * NT1 + 255) / 256, 256, 0, stream>>>(W1, Wh1, Wl1, 128, NT1);
    wprep_frag<<<(F_IN * NT2 + 255) / 256, 256, 0, stream>>>(W2, Wh2, Wl2, 64, NT2);

    for (int b0 = 0; b0 < BATCH; b0 += Bc) {
        int bc = (BATCH - b0 < Bc) ? (BATCH - b0) : Bc;
        int nrows = bc * N_NODES;
        int row0 = b0 * N_NODES;

        // ---- gconv1 ----
        gemm_proj<0><<<dim3(NT1 / 64, nrows / 128), 256, 0, stream>>>(
            inp, hx, nullptr, Wh1, Wl1, Pg1, nrows, row0);
        size_t sl1 = (size_t)16 * nrows * 8;     // slice stride (floats)
        dim3 dg1(16, bc);
        diffuse_t<1><<<dg1, 256, 0, stream>>>(cnt0, ell0, Pg1 + 3 * sl1, Pg1 + 1 * sl1, Pg1 + 1 * sl1, nrows);
        diffuse_t<0><<<dg1, 256, 0, stream>>>(cnt0, ell0, Pg1 + 1 * sl1, Pg1 + 1 * sl1, nullptr, nrows);
        diffuse_t<1><<<dg1, 256, 0, stream>>>(cnt1, ell1, Pg1 + 4 * sl1, Pg1 + 2 * sl1, Pg1 + 2 * sl1, nrows);
        diffuse_t<0><<<dg1, 256, 0, stream>>>(cnt1, ell1, Pg1 + 2 * sl1, Pg1 + 2 * sl1, nullptr, nrows);
        combine1<<<dim3(nrows / 256, 16), 256, 0, stream>>>(Pg1, b1, O1t, nrows);

        // ---- gconv2 ----
        gemm_proj<1><<<dim3(NT2 / 64, nrows / 128), 256, 0, stream>>>(
            inp, hx, O1t, Wh2, Wl2, Pg2, nrows, row0);
        size_t sl2 = (size_t)8 * nrows * 8;
        dim3 dg2(8, bc);
        diffuse_t<1><<<dg2, 256, 0, stream>>>(cnt0, ell0, Pg2 + 3 * sl2, Pg2 + 1 * sl2, Pg2 + 1 * sl2, nrows);
        diffuse_t<0><<<dg2, 256, 0, stream>>>(cnt0, ell0, Pg2 + 1 * sl2, Pg2 + 1 * sl2, nullptr, nrows);
        diffuse_t<1><<<dg2, 256, 0, stream>>>(cnt1, ell1, Pg2 + 4 * sl2, Pg2 + 2 * sl2, Pg2 + 2 * sl2, nrows);
        diffuse_t<0><<<dg2, 256, 0, stream>>>(cnt1, ell1, Pg2 + 2 * sl2, Pg2 + 2 * sl2, nullptr, nrows);
        combine2<<<dim3(nrows / 256, 8), 256, 0, stream>>>(Pg2, b2, O1t, hx, out, nrows, row0);
    }
}

// Round 7
// 585.812 us; speedup vs baseline: 1.3051x; 1.3051x over previous
//
#include <hip/hip_runtime.h>
#include <math.h>

#define N_NODES 1024
#define BATCH   64
#define F_IN    128     // D_IN + UNITS (K of the projection GEMM)
#define UNITS   64
#define NUM_M   5
#define CAP     192     // ELL row capacity (max row degree ~55 for this seed)
#define NT1     640     // 5*128 output cols, gconv1
#define NT2     320     // 5*64  output cols, gconv2

typedef __attribute__((ext_vector_type(8))) short short8v;
typedef __attribute__((ext_vector_type(4))) float f32x4;

__device__ __forceinline__ unsigned short bf16_rne(float x) {
    unsigned u = __float_as_uint(x);
    return (unsigned short)((u + 0x7FFFu + ((u >> 16) & 1u)) >> 16);
}

// ---------------- ELL build: column-major packed (col,val), zero-filled -----
// ell[j*1024 + row] = float2(col_bits, val); zero-filled to CAP so gathers may
// overrun a row's count harmlessly. cnt[row] = nnz padded to x4.
__global__ void ell_build(const float* __restrict__ L, int* __restrict__ cnt,
                          float2* __restrict__ ell) {
    int row  = blockIdx.x * (blockDim.x >> 6) + (threadIdx.x >> 6);
    int lane = threadIdx.x & 63;
    if (row >= N_NODES) return;
    const float* Lr = L + (size_t)row * N_NODES;
    int base = 0;
    for (int seg = 0; seg < N_NODES; seg += 64) {
        float v = Lr[seg + lane];
        bool nz = (v != 0.0f);
        unsigned long long bal = __ballot(nz);
        int off = __popcll(bal & ((1ull << lane) - 1ull));
        if (nz) {
            int idx = base + off;
            if (idx < CAP) ell[(size_t)idx * N_NODES + row] =
                               make_float2(__int_as_float(seg + lane), v);
        }
        base += __popcll(bal);
    }
    if (base > CAP) base = CAP;
    for (int idx = base + lane; idx < CAP; idx += 64)
        ell[(size_t)idx * N_NODES + row] = make_float2(__int_as_float(0), 0.0f);
    if (lane == 0) cnt[row] = (base + 3) & ~3;
}

// ---------------- W' prep: fold + bf16 hi/lo split + MFMA fragment order ----
// W [640][nout], row = k*5 + m. Folded W'[k][jg], jg = m*nout + j:
//   m0 = W0-W3-W4, m1 = W1, m2 = W2, m3 = 2*W3, m4 = 2*W4
// Fragment layout (16x16x32 bf16 B-operand): element (k, jg) at
//   ((((jg>>4)*4 + (k>>5))*64) + ((k>>3)&3)*16 + (jg&15))*8 + (k&7)
__global__ void wprep_frag(const float* __restrict__ W, unsigned short* __restrict__ Wh,
                           unsigned short* __restrict__ Wl, int nout, int ntot) {
    int idx = blockIdx.x * blockDim.x + threadIdx.x;
    if (idx >= F_IN * ntot) return;
    int jg = idx % ntot, k = idx / ntot;
    int m = jg / nout, j = jg % nout;
    const float* Wk = W + (size_t)(k * NUM_M) * nout;
    float v;
    if (m == 0)      v = Wk[0 * nout + j] - Wk[3 * nout + j] - Wk[4 * nout + j];
    else if (m == 3) v = 2.0f * Wk[3 * nout + j];
    else if (m == 4) v = 2.0f * Wk[4 * nout + j];
    else             v = Wk[(size_t)m * nout + j];
    unsigned short h = bf16_rne(v);
    float hf = __uint_as_float((unsigned)h << 16);
    unsigned short lo = bf16_rne(v - hf);
    size_t fi = ((((size_t)(jg >> 4) * 4 + (k >> 5)) * 64) + ((k >> 3) & 3) * 16 + (jg & 15)) * 8 + (k & 7);
    Wh[fi] = h; Wl[fi] = lo;
}

// ---------------- MFMA projection v2: direct A loads, LDS store-transpose ---
// grid = (NT/64, nrows/128); block 256 (4 waves, 2 row-halves x 2 col-halves).
// A-fragments loaded straight from global (8 contiguous k per lane), bf16
// hi/lo in-register. Output transposed through 34.8 KB LDS -> coalesced
// stores into tiled P layout: P[(jg>>3)*nrows*8 + i*8 + (jg&7)].
template <int RMUL>
__global__ __launch_bounds__(256, 3) void gemm_proj(
        const float* __restrict__ inp, const float* __restrict__ hx,
        const float* __restrict__ r1t,       // OUT1 tiled; tiles 0-7 = r
        const unsigned short* __restrict__ Wh, const unsigned short* __restrict__ Wl,
        float* __restrict__ P, int nrows, int row0) {
    __shared__ float sc[128][68];
    const int tid = threadIdx.x;
    const int i0 = blockIdx.y * 128;
    const int by = blockIdx.x;
    const int lane = tid & 63, wid = tid >> 6;
    const int wm = wid >> 1, wn = wid & 1;
    const int l15 = lane & 15, l4 = lane >> 4;

    // B fragments from pre-packed Wh/Wl (L2-resident)
    short8v bh[4][2], bl[4][2];
    #pragma unroll
    for (int s = 0; s < 4; ++s)
        #pragma unroll
        for (int jc = 0; jc < 2; ++jc) {
            int cg16 = by * 4 + wn * 2 + jc;
            size_t o = (((size_t)cg16 * 4 + s) * 64 + lane) * 8;
            bh[s][jc] = *(const short8v*)(Wh + o);
            bl[s][jc] = *(const short8v*)(Wl + o);
        }

    f32x4 acc[4][2];
    #pragma unroll
    for (int i = 0; i < 4; ++i)
        #pragma unroll
        for (int jc = 0; jc < 2; ++jc)
            acc[i][jc] = (f32x4){0.f, 0.f, 0.f, 0.f};

    #pragma unroll
    for (int s = 0; s < 4; ++s) {
        const int kg8 = s * 4 + l4;          // 0..15; s<2 -> inp, s>=2 -> hx
        short8v ah[4], al[4];
        #pragma unroll
        for (int i = 0; i < 4; ++i) {
            int row_l = i0 + wm * 64 + i * 16 + l15;
            size_t g = (size_t)(row0 + row_l);
            float x[8];
            if (s < 2) {
                *(float4*)&x[0] = *(const float4*)(inp + g * 64 + kg8 * 8);
                *(float4*)&x[4] = *(const float4*)(inp + g * 64 + kg8 * 8 + 4);
            } else {
                *(float4*)&x[0] = *(const float4*)(hx + g * 64 + (kg8 - 8) * 8);
                *(float4*)&x[4] = *(const float4*)(hx + g * 64 + (kg8 - 8) * 8 + 4);
                if (RMUL) {
                    const float* rp = r1t + ((size_t)(kg8 - 8) * nrows + row_l) * 8;
                    float4 r0 = *(const float4*)rp, r4 = *(const float4*)(rp + 4);
                    x[0] *= r0.x; x[1] *= r0.y; x[2] *= r0.z; x[3] *= r0.w;
                    x[4] *= r4.x; x[5] *= r4.y; x[6] *= r4.z; x[7] *= r4.w;
                }
            }
            #pragma unroll
            for (int e = 0; e < 8; ++e) {
                unsigned short h = bf16_rne(x[e]);
                ah[i][e] = (short)h;
                al[i][e] = (short)bf16_rne(x[e] - __uint_as_float((unsigned)h << 16));
            }
        }
        #pragma unroll
        for (int i = 0; i < 4; ++i)
            #pragma unroll
            for (int jc = 0; jc < 2; ++jc) {
                acc[i][jc] = __builtin_amdgcn_mfma_f32_16x16x32_bf16(al[i], bh[s][jc], acc[i][jc], 0, 0, 0);
                acc[i][jc] = __builtin_amdgcn_mfma_f32_16x16x32_bf16(ah[i], bl[s][jc], acc[i][jc], 0, 0, 0);
                acc[i][jc] = __builtin_amdgcn_mfma_f32_16x16x32_bf16(ah[i], bh[s][jc], acc[i][jc], 0, 0, 0);
            }
    }

    // transpose through LDS (2-way bank aliasing only), then coalesced stores
    #pragma unroll
    for (int i = 0; i < 4; ++i)
        #pragma unroll
        for (int jc = 0; jc < 2; ++jc)
            #pragma unroll
            for (int q = 0; q < 4; ++q)
                sc[wm * 64 + i * 16 + l4 * 4 + q][wn * 32 + jc * 16 + l15] = acc[i][jc][q];
    __syncthreads();
    const int row = tid >> 1, half = tid & 1;
    #pragma unroll
    for (int t = 0; t < 8; ++t) {
        float4 v = *(const float4*)(&sc[row][t * 8 + half * 4]);
        *(float4*)(P + ((size_t)(by * 8 + t) * nrows + (i0 + row)) * 8 + half * 4) = v;
    }
}

// ---------------- ILP gather: 4 interleaved rows, j-outer ------------------
// Loops to max(cnt) of the 4 rows; overrun entries are (0,0) -> harmless.
__device__ __forceinline__ void gather4(
        const int* __restrict__ cnt, const float2* __restrict__ ell,
        const float* __restrict__ ldsX, int mg, int fg, int kbase, float4* accR) {
    int m[4], nn[4];
    #pragma unroll
    for (int k = 0; k < 4; ++k) { m[k] = mg + (kbase + k) * 128; nn[k] = cnt[m[k]]; }
    int nmax = max(max(nn[0], nn[1]), max(nn[2], nn[3]));
    float4 acc[4];
    #pragma unroll
    for (int k = 0; k < 4; ++k) acc[k] = make_float4(0.f, 0.f, 0.f, 0.f);
    for (int j = 0; j < nmax; j += 4) {
        float2 e[4][4];
        #pragma unroll
        for (int k = 0; k < 4; ++k)
            #pragma unroll
            for (int u = 0; u < 4; ++u)
                e[k][u] = ell[(size_t)(j + u) * N_NODES + m[k]];
        #pragma unroll
        for (int k = 0; k < 4; ++k)
            #pragma unroll
            for (int u = 0; u < 4; ++u) {
                float4 x = *(const float4*)(ldsX + __float_as_int(e[k][u].x) * 8 + fg * 4);
                acc[k].x += e[k][u].y * x.x; acc[k].y += e[k][u].y * x.y;
                acc[k].z += e[k][u].y * x.z; acc[k].w += e[k][u].y * x.w;
            }
    }
    #pragma unroll
    for (int k = 0; k < 4; ++k) accR[k] = acc[k];
}

// ---------------- diffuse2: S = L @ (addK1 + L @ srcK2), fused 2-step -------
// One 8-col tile per block; 32 KB LDS reused for both passes (T overwrites
// the staged srcK2 tile between barriers). dst may alias addK1 (in-place):
// every block touches only its own (tile, batch) range of all three streams.
__global__ __launch_bounds__(256, 4) void diffuse2(
        const int* __restrict__ cnt, const float2* __restrict__ ell,
        const float* __restrict__ srcK2, const float* __restrict__ addK1,
        float* __restrict__ dst, int nrows) {
    __shared__ float ldsX[N_NODES * 8];   // 32 KB
    const int tid = threadIdx.x;
    const size_t base = ((size_t)blockIdx.x * nrows + blockIdx.y * N_NODES) * 8;

    for (int v = tid; v < 2048; v += 256)
        *(float4*)(ldsX + v * 4) = *(const float4*)(srcK2 + base + v * 4);
    __syncthreads();

    const int fg = tid & 1, mg = tid >> 1;
    float4 T[8];
    gather4(cnt, ell, ldsX, mg, fg, 0, T);
    gather4(cnt, ell, ldsX, mg, fg, 4, T + 4);
    __syncthreads();                         // all pass-1 reads complete
    #pragma unroll
    for (int k = 0; k < 8; ++k) {
        int mm = mg + k * 128;
        float4 a = *(const float4*)(addK1 + base + (size_t)mm * 8 + fg * 4);
        T[k].x += a.x; T[k].y += a.y; T[k].z += a.z; T[k].w += a.w;
        *(float4*)(ldsX + mm * 8 + fg * 4) = T[k];
    }
    __syncthreads();
    float4 S[8];
    gather4(cnt, ell, ldsX, mg, fg, 0, S);
    gather4(cnt, ell, ldsX, mg, fg, 4, S + 4);
    #pragma unroll
    for (int k = 0; k < 8; ++k)
        *(float4*)(dst + base + (size_t)(mg + k * 128) * 8 + fg * 4) = S[k];
}

// ---------------- combine1: OUT1 = sigmoid(P0+S1+S2+b1), tiled out ---------
__global__ void combine1(const float* __restrict__ P, const float* __restrict__ b1,
                         float* __restrict__ O1, int nrows) {
    int i  = blockIdx.x * 256 + threadIdx.x;
    int ft = blockIdx.y;                       // 0..15
    size_t sl = (size_t)16 * nrows * 8;
    size_t o  = ((size_t)ft * nrows + i) * 8;
    #pragma unroll
    for (int q = 0; q < 8; q += 4) {
        float4 p0 = *(const float4*)(P + o + q);
        float4 p1 = *(const float4*)(P + sl + o + q);
        float4 p2 = *(const float4*)(P + 2 * sl + o + q);
        float4 bb = *(const float4*)(b1 + ft * 8 + q);
        float4 z;
        z.x = 1.f / (1.f + expf(-(p0.x + p1.x + p2.x + bb.x)));
        z.y = 1.f / (1.f + expf(-(p0.y + p1.y + p2.y + bb.y)));
        z.z = 1.f / (1.f + expf(-(p0.z + p1.z + p2.z + bb.z)));
        z.w = 1.f / (1.f + expf(-(p0.w + p1.w + p2.w + bb.w)));
        *(float4*)(O1 + o + q) = z;
    }
}

// ---------------- combine2: out = u*hx + (1-u)*tanh(P0+S1+S2+b2) -----------
__global__ void combine2(const float* __restrict__ P, const float* __restrict__ b2,
                         const float* __restrict__ O1, const float* __restrict__ hx,
                         float* __restrict__ out, int nrows, int row0) {
    int i  = blockIdx.x * 256 + threadIdx.x;
    int ft = blockIdx.y;                       // 0..7
    size_t sl = (size_t)8 * nrows * 8;
    size_t o  = ((size_t)ft * nrows + i) * 8;
    size_t ou = ((size_t)(8 + ft) * nrows + i) * 8;
    size_t g  = (size_t)(row0 + i) * 64 + ft * 8;
    #pragma unroll
    for (int q = 0; q < 8; q += 4) {
        float4 p0 = *(const float4*)(P + o + q);
        float4 p1 = *(const float4*)(P + sl + o + q);
        float4 p2 = *(const float4*)(P + 2 * sl + o + q);
        float4 bb = *(const float4*)(b2 + ft * 8 + q);
        float4 u  = *(const float4*)(O1 + ou + q);
        float4 h  = *(const float4*)(hx + g + q);
        float4 r;
        float c;
        c = tanhf(p0.x + p1.x + p2.x + bb.x); r.x = u.x * h.x + (1.f - u.x) * c;
        c = tanhf(p0.y + p1.y + p2.y + bb.y); r.y = u.y * h.y + (1.f - u.y) * c;
        c = tanhf(p0.z + p1.z + p2.z + bb.z); r.z = u.z * h.z + (1.f - u.z) * c;
        c = tanhf(p0.w + p1.w + p2.w + bb.w); r.w = u.w * h.w + (1.f - u.w) * c;
        *(float4*)(out + g + q) = r;
    }
}

// ---------------------------------------------------------------------------
extern "C" void kernel_launch(void* const* d_in, const int* in_sizes, int n_in,
                              void* d_out, int out_size, void* d_ws, size_t ws_size,
                              hipStream_t stream) {
    const float* inp = (const float*)d_in[0];
    const float* hx  = (const float*)d_in[1];
    const float* L0  = (const float*)d_in[2];
    const float* L1  = (const float*)d_in[3];
    const float* W1  = (const float*)d_in[4];
    const float* b1  = (const float*)d_in[5];
    const float* W2  = (const float*)d_in[6];
    const float* b2  = (const float*)d_in[7];
    float* out = (float*)d_out;

    char* ws = (char*)d_ws;
    size_t off = 0;
    auto carve = [&](size_t bytes) -> char* {
        off = (off + 255) & ~(size_t)255;
        char* p = ws + off;
        off += bytes;
        return p;
    };
    // fixed region
    int*    cnt0 = (int*)   carve(N_NODES * sizeof(int));
    float2* ell0 = (float2*)carve((size_t)N_NODES * CAP * sizeof(float2));
    int*    cnt1 = (int*)   carve(N_NODES * sizeof(int));
    float2* ell1 = (float2*)carve((size_t)N_NODES * CAP * sizeof(float2));
    unsigned short* Wh1 = (unsigned short*)carve((size_t)F_IN * NT1 * 2);
    unsigned short* Wl1 = (unsigned short*)carve((size_t)F_IN * NT1 * 2);
    unsigned short* Wh2 = (unsigned short*)carve((size_t)F_IN * NT2 * 2);
    unsigned short* Wl2 = (unsigned short*)carve((size_t)F_IN * NT2 * 2);

    // chunking (power-of-two Bc)
    size_t per_batch = (size_t)N_NODES * (NT1 + F_IN + NT2) * sizeof(float);   // ~4.45 MB
    size_t fixed_end = (off + 255) & ~(size_t)255;
    size_t avail = (ws_size > fixed_end + 4096) ? (ws_size - fixed_end - 4096) : per_batch;
    int maxb = (int)(avail / per_batch);
    int Bc = 1;
    while (Bc * 2 <= maxb && Bc * 2 <= BATCH) Bc *= 2;

    float* Pg1  = (float*)carve((size_t)Bc * N_NODES * NT1 * sizeof(float));
    float* O1t  = (float*)carve((size_t)Bc * N_NODES * F_IN * sizeof(float));
    float* Pg2  = (float*)carve((size_t)Bc * N_NODES * NT2 * sizeof(float));

    ell_build<<<N_NODES / 4, 256, 0, stream>>>(L0, cnt0, ell0);
    ell_build<<<N_NODES / 4, 256, 0, stream>>>(L1, cnt1, ell1);
    wprep_frag<<<(F_IN * NT1 + 255) / 256, 256, 0, stream>>>(W1, Wh1, Wl1, 128, NT1);
    wprep_frag<<<(F_IN * NT2 + 255) / 256, 256, 0, stream>>>(W2, Wh2, Wl2, 64, NT2);

    for (int b0 = 0; b0 < BATCH; b0 += Bc) {
        int bc = (BATCH - b0 < Bc) ? (BATCH - b0) : Bc;
        int nrows = bc * N_NODES;
        int row0 = b0 * N_NODES;

        // ---- gconv1 ----
        gemm_proj<0><<<dim3(NT1 / 64, nrows / 128), 256, 0, stream>>>(
            inp, hx, nullptr, Wh1, Wl1, Pg1, nrows, row0);
        size_t sl1 = (size_t)16 * nrows * 8;     // 128-col slice stride (floats)
        dim3 dg1(16, bc);
        diffuse2<<<dg1, 256, 0, stream>>>(cnt0, ell0, Pg1 + 3 * sl1, Pg1 + 1 * sl1, Pg1 + 1 * sl1, nrows);
        diffuse2<<<dg1, 256, 0, stream>>>(cnt1, ell1, Pg1 + 4 * sl1, Pg1 + 2 * sl1, Pg1 + 2 * sl1, nrows);
        combine1<<<dim3(nrows / 256, 16), 256, 0, stream>>>(Pg1, b1, O1t, nrows);

        // ---- gconv2 ----
        gemm_proj<1><<<dim3(NT2 / 64, nrows / 128), 256, 0, stream>>>(
            inp, hx, O1t, Wh2, Wl2, Pg2, nrows, row0);
        size_t sl2 = (size_t)8 * nrows * 8;      // 64-col slice stride (floats)
        dim3 dg2(8, bc);
        diffuse2<<<dg2, 256, 0, stream>>>(cnt0, ell0, Pg2 + 3 * sl2, Pg2 + 1 * sl2, Pg2 + 1 * sl2, nrows);
        diffuse2<<<dg2, 256, 0, stream>>>(cnt1, ell1, Pg2 + 4 * sl2, Pg2 + 2 * sl2, Pg2 + 2 * sl2, nrows);
        combine2<<<dim3(nrows / 256, 8), 256, 0, stream>>>(Pg2, b2, O1t, hx, out, nrows, row0);
    }
}